// Round 6
// baseline (36.926 us; speedup 1.0000x reference)
//
#include <hip/hip_runtime.h>
#include <hip/hip_bf16.h>

// LinearCombiner: MLP has NO activation -> affine: out = M@x + c,
// M = W3@W2@W1 (8x3072), c = (W3@W2)@b1 + W3@b2 + b3, and
// x[t,u] = [min;max;user] separable -> out[t,u,o] = P[t,o]+Q[u,o]+c[o].
//
// 4 launches (3 gaps; round-5 showed ~4us/gap dominates):
//  K1 gemm (mode 0): part1 = W3@W2 partials (+ cp2[s] = W3_slice . b2)
//  K2 gemm (mode 1): A = self-reduced M2 slice from part1, part2 = M2@W1 (+cp1)
//  K3 mid: blocks 0..15  : M_text[8][2048] = reduce_s part2 (text cols only)
//          blocks 16..23 : Qpart[dg][u][o] — reduce M_user 128-col strip from
//                          part2, then project against user (M_user never hits ws)
//  K4 out: 256 t-blocks: P[t]=M_text.[min;max], Q=sum_dg Qpart, c from cp1/cp2,
//          write out[t,:,:]  (combine fused; c recomputed per block, 512 floats)

#define HIDN 3072
#define DIM 1024
#define NOUT 8
#define NS 32            // k-slices
#define KPS 96           // rows per slice
#define WK 24            // rows per wave (KPS/4)
#define GX 12            // column groups of 256 cols
#define TDIM 256
#define UDIM 128

__device__ __forceinline__ float dot4(float4 a, float4 b) {
    return a.x * b.x + a.y * b.y + a.z * b.z + a.w * b.w;
}
__device__ __forceinline__ float4 add4(float4 a, float4 b) {
    return make_float4(a.x + b.x, a.y + b.y, a.z + b.z, a.w + b.w);
}

// fold cp[s][o] = sum_kk As[o][kk] * bvec[s*KPS+kk]  (32 lanes per o)
__device__ __forceinline__ void bias_slice_fold(const float* As,
                                                const float* __restrict__ bvec,
                                                float* __restrict__ cp,
                                                int s, int tid) {
    const int o = tid >> 5, k5 = tid & 31;
    float acc = 0.f;
#pragma unroll
    for (int j = 0; j < KPS / 32; ++j)
        acc += As[o * KPS + k5 + 32 * j] * bvec[s * KPS + k5 + 32 * j];
#pragma unroll
    for (int off = 16; off; off >>= 1) acc += __shfl_down(acc, off, 32);
    if (k5 == 0) cp[s * NOUT + o] = acc;
}

// mode 0: A_rows (8,HIDN) read directly. mode 1: A slice self-reduced from
// part_in. part_out[s][o][h] = sum_{k in slice s} A[o,k] * B[k,h]
__global__ __launch_bounds__(256) void gemm_partial(
    const float* __restrict__ A_rows, const float* __restrict__ part_in,
    const float* __restrict__ B, float* __restrict__ part_out,
    const float* __restrict__ bvec, float* __restrict__ cp, int mode) {
    const int s = blockIdx.y, gx = blockIdx.x;
    const int tid = threadIdx.x;
    const int lane = tid & 63, w = tid >> 6;

    __shared__ float As[NOUT * KPS];          // 3 KB
    __shared__ float4 red[4 * NOUT * 64];     // 32 KB

    if (mode == 0) {
        for (int i = tid; i < NOUT * KPS; i += 256)
            As[i] = A_rows[(i / KPS) * HIDN + s * KPS + (i % KPS)];
    } else {
        for (int j4 = tid; j4 < NOUT * KPS / 4; j4 += 256) {
            const int o = j4 / (KPS / 4), kk4 = j4 % (KPS / 4);
            const float4* pp = (const float4*)(part_in + (size_t)o * HIDN
                                               + s * KPS) + kk4;
            float4 a = make_float4(0.f, 0.f, 0.f, 0.f);
#pragma unroll 8
            for (int sp = 0; sp < NS; ++sp)
                a = add4(a, pp[(size_t)sp * (NOUT * HIDN / 4)]);
            ((float4*)As)[j4] = a;
        }
    }
    __syncthreads();
    if (gx == 0) bias_slice_fold(As, bvec, cp, s, tid);

    const int h = gx * 256 + lane * 4;
    const int k0 = s * KPS + w * WK;
    const float4* Bp = (const float4*)(B + (size_t)k0 * HIDN) + (h >> 2);

    float4 bv[WK];                             // 24 hoisted loads, ~24KB/wave
#pragma unroll
    for (int kk = 0; kk < WK; ++kk) bv[kk] = Bp[(size_t)kk * (HIDN / 4)];

    float4 acc[NOUT];
#pragma unroll
    for (int o = 0; o < NOUT; ++o) acc[o] = make_float4(0.f, 0.f, 0.f, 0.f);
#pragma unroll
    for (int kk = 0; kk < WK; ++kk) {
#pragma unroll
        for (int o = 0; o < NOUT; ++o) {
            float a = As[o * KPS + w * WK + kk];
            acc[o].x += a * bv[kk].x; acc[o].y += a * bv[kk].y;
            acc[o].z += a * bv[kk].z; acc[o].w += a * bv[kk].w;
        }
    }

#pragma unroll
    for (int o = 0; o < NOUT; ++o) red[(w * NOUT + o) * 64 + lane] = acc[o];
    __syncthreads();
#pragma unroll
    for (int j = 0; j < 2; ++j) {
        const int o = w * 2 + j;
        float4 r = add4(add4(red[(0 * NOUT + o) * 64 + lane],
                             red[(1 * NOUT + o) * 64 + lane]),
                        add4(red[(2 * NOUT + o) * 64 + lane],
                             red[(3 * NOUT + o) * 64 + lane]));
        *(float4*)(part_out + ((size_t)s * NOUT + o) * HIDN + h) = r;
    }
}

// blocks 0..15 : Mt (8x2048) = sum_s part2[s][o][0:2048]
// blocks 16..23: Qpart[dg][u][o] = sum_{d in dg strip} Mu[o,d]*user[u,d],
//                Mu strip reduced from part2 in LDS first.
__global__ __launch_bounds__(256) void mid_kernel(const float* __restrict__ part2,
                                                  const float* __restrict__ user,
                                                  float* __restrict__ Mt,
                                                  float* __restrict__ Qpart) {
    const int b = blockIdx.x, tid = threadIdx.x;
    const float4* p4 = (const float4*)part2;

    if (b < 16) {                      // Mt reduce: 16 blocks x 256 f4 = 4096 f4
        const int i4 = b * 256 + tid;          // [0, 4096)
        const int o = i4 >> 9, j4 = i4 & 511;  // col4 in [0,512) -> cols 0..2047
        float4 a = make_float4(0.f, 0.f, 0.f, 0.f);
#pragma unroll 8
        for (int s = 0; s < NS; ++s)
            a = add4(a, p4[((size_t)s * NOUT + o) * (HIDN / 4) + j4]);
        ((float4*)Mt)[o * 512 + j4] = a;
        return;
    }

    // --- Q partial for d-group dg (128 user-dims) ---
    const int dg = b - 16;
    __shared__ float4 Mu4[NOUT * 32];          // Mu[8][128] as f4
    {
        const int o = tid >> 5, j4 = tid & 31;
        float4 a = make_float4(0.f, 0.f, 0.f, 0.f);
#pragma unroll 8
        for (int s = 0; s < NS; ++s)
            a = add4(a, p4[((size_t)s * NOUT + o) * (HIDN / 4) + 512 + dg * 32 + j4]);
        Mu4[o * 32 + j4] = a;
    }
    __syncthreads();

    // thread -> (u = tid/2, o0 = (tid&1)*4): 4 outputs, each 128-MAC
    const int u = tid >> 1, o0 = (tid & 1) * 4;
    const float4* uv = (const float4*)(user) + u * (DIM / 4) + dg * 32;
    float q[4] = {0.f, 0.f, 0.f, 0.f};
    for (int j = 0; j < 32; ++j) {
        float4 x = uv[j];
#pragma unroll
        for (int oo = 0; oo < 4; ++oo)
            q[oo] += dot4(Mu4[(o0 + oo) * 32 + j], x);
    }
    *(float4*)(Qpart + ((size_t)dg * UDIM + u) * NOUT + o0) =
        make_float4(q[0], q[1], q[2], q[3]);
}

// 256 t-blocks: P[t] from Mt, Q from Qpart, c from cp1/cp2/b3; write out row.
__global__ __launch_bounds__(256) void out_kernel(
    const float* __restrict__ ta, const float* __restrict__ tb,
    const float* __restrict__ Mt, const float* __restrict__ Qpart,
    const float* __restrict__ cp1, const float* __restrict__ cp2,
    const float* __restrict__ b3, float4* __restrict__ out) {
    const int t = blockIdx.x, tid = threadIdx.x;
    const int lane = tid & 63, w = tid >> 6;

    // ---- P[t,o]: thread owns one f4 of the 1024 text dims ----
    const float4* Mt4 = (const float4*)Mt;
    float4 a = ((const float4*)ta)[t * (DIM / 4) + tid];
    float4 b = ((const float4*)tb)[t * (DIM / 4) + tid];
    float4 mn = make_float4(fminf(a.x, b.x), fminf(a.y, b.y),
                            fminf(a.z, b.z), fminf(a.w, b.w));
    float4 mx = make_float4(fmaxf(a.x, b.x), fmaxf(a.y, b.y),
                            fmaxf(a.z, b.z), fmaxf(a.w, b.w));
    float acc[NOUT];
#pragma unroll
    for (int o = 0; o < NOUT; ++o) {
        float4 ml = Mt4[o * 512 + tid];          // cols 0..1023
        float4 mh = Mt4[o * 512 + 256 + tid];    // cols 1024..2047
        acc[o] = dot4(ml, mn) + dot4(mh, mx);
    }
#pragma unroll
    for (int o = 0; o < NOUT; ++o) {
#pragma unroll
        for (int off = 32; off > 0; off >>= 1)
            acc[o] += __shfl_down(acc[o], off, 64);
    }
    __shared__ float red[4][NOUT];
    __shared__ float c8[NOUT];
    if (lane == 0) {
#pragma unroll
        for (int o = 0; o < NOUT; ++o) red[w][o] = acc[o];
    }

    // ---- Q for this thread's out-f4: u = tid/2, o0 = (tid&1)*4 ----
    const int u = tid >> 1, half = tid & 1;
    const float4* Qp4 = (const float4*)Qpart;
    float4 q = make_float4(0.f, 0.f, 0.f, 0.f);
#pragma unroll
    for (int dg = 0; dg < 8; ++dg)
        q = add4(q, Qp4[((size_t)dg * UDIM + u) * 2 + half]);

    // ---- c (redundant per block, 512 floats) ----
    if (tid < NOUT) {
        float cc = b3[tid];
#pragma unroll 8
        for (int s = 0; s < NS; ++s)
            cc += cp1[s * NOUT + tid] + cp2[s * NOUT + tid];
        c8[tid] = cc;
    }
    __syncthreads();

    const int o0 = half * 4;
    float4 pv = make_float4(
        red[0][o0 + 0] + red[1][o0 + 0] + red[2][o0 + 0] + red[3][o0 + 0],
        red[0][o0 + 1] + red[1][o0 + 1] + red[2][o0 + 1] + red[3][o0 + 1],
        red[0][o0 + 2] + red[1][o0 + 2] + red[2][o0 + 2] + red[3][o0 + 2],
        red[0][o0 + 3] + red[1][o0 + 3] + red[2][o0 + 3] + red[3][o0 + 3]);
    float4 cv = make_float4(c8[o0], c8[o0 + 1], c8[o0 + 2], c8[o0 + 3]);
    out[(size_t)t * 256 + tid] = add4(add4(pv, q), cv);
}

extern "C" void kernel_launch(void* const* d_in, const int* in_sizes, int n_in,
                              void* d_out, int out_size, void* d_ws, size_t ws_size,
                              hipStream_t stream) {
    const float* text_a = (const float*)d_in[0];
    const float* text_b = (const float*)d_in[1];
    const float* user   = (const float*)d_in[2];
    const float* W1 = (const float*)d_in[3];
    const float* b1 = (const float*)d_in[4];
    const float* W2 = (const float*)d_in[5];
    const float* b2 = (const float*)d_in[6];
    const float* W3 = (const float*)d_in[7];
    const float* b3 = (const float*)d_in[8];

    float* ws = (float*)d_ws;
    float* part1 = ws;                                  // 786432 floats
    float* part2 = part1 + (size_t)NS * NOUT * HIDN;    // 786432
    float* Mt    = part2 + (size_t)NS * NOUT * HIDN;    // 16384 (8x2048)
    float* Qpart = Mt + NOUT * 2048;                    // 8192  (8x128x8)
    float* cp1   = Qpart + 8 * UDIM * NOUT;             // 256
    float* cp2   = cp1 + NS * NOUT;                     // 256

    // K1: part1 = W3 @ W2 ; cp2
    gemm_partial<<<dim3(GX, NS), 256, 0, stream>>>(W3, nullptr, W2, part1,
                                                   b2, cp2, 0);
    // K2: part2 = M2 @ W1 (self-reduced A) ; cp1
    gemm_partial<<<dim3(GX, NS), 256, 0, stream>>>(nullptr, part1, W1, part2,
                                                   b1, cp1, 1);
    // K3: Mt reduce + Qpart
    mid_kernel<<<24, 256, 0, stream>>>(part2, user, Mt, Qpart);
    // K4: P + Q + c -> out
    out_kernel<<<TDIM, 256, 0, stream>>>(text_a, text_b, Mt, Qpart,
                                         cp1, cp2, b3, (float4*)d_out);
}